// Round 9
// baseline (1372.412 us; speedup 1.0000x reference)
//
#include <hip/hip_runtime.h>
#include <hip/hip_bf16.h>
#include <hip/hip_fp16.h>

#define T_STEPS 512
#define BATCH   64
#define DIM     512            // INPUT_DIM == RNN_DIM

typedef _Float16 half2_t __attribute__((ext_vector_type(2)));
typedef _Float16 half4_t __attribute__((ext_vector_type(4)));
typedef _Float16 half8_t __attribute__((ext_vector_type(8)));
typedef short    bf16x8 __attribute__((ext_vector_type(8)));
typedef float    f32x4  __attribute__((ext_vector_type(4)));

static __device__ __forceinline__ unsigned short f2bf(float f) {
    union { float f; unsigned u; } v; v.f = f;
    unsigned r = v.u + 0x7fffu + ((v.u >> 16) & 1u);   // RNE
    return (unsigned short)(r >> 16);
}

static __device__ __forceinline__ float fast_tanh(float x) {
    float e = __expf(2.0f * x);
    return 1.0f - 2.0f * __builtin_amdgcn_rcpf(e + 1.0f);
}

// ------------- K1: transpose 512x512 fp32 region -> bf16 (for Wx^T, gemm B-operand) -------------
__global__ __launch_bounds__(256) void tr_cvt_kernel(const float* __restrict__ src,
                                                     unsigned short* __restrict__ dst) {
    __shared__ float tile[32][33];
    const int bx = blockIdx.x * 32;
    const int by = blockIdx.y * 32;
    const int tx = threadIdx.x;       // 32
    const int ty = threadIdx.y;       // 8
    #pragma unroll
    for (int i = ty; i < 32; i += 8)
        tile[i][tx] = src[(size_t)(by + i) * DIM + (bx + tx)];
    __syncthreads();
    #pragma unroll
    for (int i = ty; i < 32; i += 8)
        dst[(size_t)(bx + i) * DIM + (by + tx)] = f2bf(tile[tx][i]);
}

// ------------- K1c: transpose Wh (rows 512..1023 of W) -> f16 WhT[col][k] -------------
__global__ __launch_bounds__(256) void tr_cvt_f16_kernel(const float* __restrict__ src,  // W + 512*512
                                                         _Float16* __restrict__ dst) {  // [512 col][512 k]
    __shared__ float tile[32][33];
    const int bx = blockIdx.x * 32;
    const int by = blockIdx.y * 32;
    const int tx = threadIdx.x;
    const int ty = threadIdx.y;
    #pragma unroll
    for (int i = ty; i < 32; i += 8)
        tile[i][tx] = src[(size_t)(by + i) * DIM + (bx + tx)];
    __syncthreads();
    #pragma unroll
    for (int i = ty; i < 32; i += 8)
        dst[(size_t)(bx + i) * DIM + (by + tx)] = (_Float16)tile[tx][i];
}

// ---------------- K2: Z = X @ Wx + bias  (bf16 MFMA), output in K3 per-thread frag order --------
// K3 thread (w, l=q*16+l15) in WG b owns Z[brow=b*16+l15][col=w*64+ct*16+q*4+rg] at i=ct*4+rg.
// Zws[t][(b*8+w)*64 + l][i]   (validated in R5/R6 runs)
__global__ __launch_bounds__(256) void gemm_z_kernel(const float* __restrict__ X,            // [32768][512] f32
                                                     const unsigned short* __restrict__ WxT, // [512 n][512 k] bf16
                                                     const float* __restrict__ bias,         // [512]
                                                     _Float16* __restrict__ Zo) {            // [512][4][8][64][16] f16
    const int bm   = blockIdx.y;
    const int bn   = blockIdx.x;
    const int wave = threadIdx.x >> 6;
    const int lane = threadIdx.x & 63;
    const int mBase = bm * 128 + (wave >> 1) * 64;
    const int nBase = bn * 128 + (wave & 1) * 64;
    const int l15 = lane & 15;
    const int q   = lane >> 4;
    f32x4 acc[4][4] = {};
    for (int kt = 0; kt < 512; kt += 32) {
        const int kk = kt + q * 8;
        bf16x8 a[4], b[4];
        #pragma unroll
        for (int i = 0; i < 4; ++i) {
            const float* ap = X + (size_t)(mBase + i * 16 + l15) * DIM + kk;
            float4 f0 = *(const float4*)(ap);
            float4 f1 = *(const float4*)(ap + 4);
            bf16x8 av;
            av[0] = (short)f2bf(f0.x); av[1] = (short)f2bf(f0.y);
            av[2] = (short)f2bf(f0.z); av[3] = (short)f2bf(f0.w);
            av[4] = (short)f2bf(f1.x); av[5] = (short)f2bf(f1.y);
            av[6] = (short)f2bf(f1.z); av[7] = (short)f2bf(f1.w);
            a[i] = av;
        }
        #pragma unroll
        for (int i = 0; i < 4; ++i)
            b[i] = *(const bf16x8*)(WxT + (size_t)(nBase + i * 16 + l15) * DIM + kk);
        #pragma unroll
        for (int mi = 0; mi < 4; ++mi)
            #pragma unroll
            for (int ni = 0; ni < 4; ++ni)
                acc[mi][ni] = __builtin_amdgcn_mfma_f32_16x16x32_bf16(a[mi], b[ni], acc[mi][ni], 0, 0, 0);
    }
    #pragma unroll
    for (int ni = 0; ni < 4; ++ni) {
        const int col = nBase + ni * 16 + l15;
        const float bv = bias[col];
        const int w_  = col >> 6;
        const int c64 = col & 63;
        const int ct_ = c64 >> 4;
        const int q_  = (c64 & 15) >> 2;
        const int rg_ = c64 & 3;
        #pragma unroll
        for (int mi = 0; mi < 4; ++mi) {
            #pragma unroll
            for (int rg = 0; rg < 4; ++rg) {
                const int row = mBase + mi * 16 + q * 4 + rg;
                const int t_ = row >> 6, batch = row & 63;
                const int b_ = batch >> 4, l15k = batch & 15;
                Zo[(size_t)t_ * 32768 + (size_t)((b_ * 8 + w_) * 64 + (q_ * 16 + l15k)) * 16 + ct_ * 4 + rg_] =
                    (_Float16)(acc[mi][ni][rg] + bv);
            }
        }
    }
}

// ---------------- K3: C^T MFMA recurrence on the EXACT R2 skeleton (best-measured: 1016 us) ----
// R2 skeleton kept: single Ah buffer (16 KB), R2 slot perm slot(L)=(L&3)*16+(L>>2), two drained
// barriers, NO setprio, 12 kt "+v"-pinned (192 regs, proven) + 4 kt LDS (128 KB, self-slots).
// ONLY delta vs R2: C^T orientation — mfma(A=W-frag, B=h-frag) so C rows=l15, cols=q*4+rg:
//   * h-writes: thread's 4 rg values = 4 CONSECUTIVE k-elems of one A-frag slot
//       -> ONE ds_write_b64 per ct (4/thread/step) instead of 16 ds_write_b16.
//       Per CU/step: 128 b16 writes -> 32 b64 writes.
//   * out-stores: 4x global_store_dwordx4 instead of 16 dwords (+ less address VALU).
// Write offset algebra (R2 slot perm): col k = wbase+ct*16+q*4+rg -> kt = w*2+(ct>>1),
//   L = ((ct&1)*2+(q>>1))*16 + l15, elem = (q&1)*4 + rg (consecutive, b64-aligned).
__global__ __launch_bounds__(512, 2) void rnn_mfma_kernel(const _Float16* __restrict__ Zw,   // [512][4][8][64][16]
                                                          const _Float16* __restrict__ WhT, // [512 col][512 k]
                                                          const float* __restrict__ h0,     // [512]
                                                          float* __restrict__ out) {        // [T][B][512]
    __shared__ _Float16 WlA[65536];   // 128 KB: (w*16 + ct*4 + ktl)*512 + l*8
    __shared__ _Float16 Ah[8192];     //  16 KB: kt*512 + slot*8 (R2 single buffer)
    const int tid = threadIdx.x;
    const int w = tid >> 6, l = tid & 63;
    const int l15 = l & 15, q = l >> 4;
    const int b = blockIdx.x;               // batch rows b*16 .. b*16+15
    const int wbase = w * 64;

    // ---- stage register A-fragments of W (kt 0..11): 192 regs (R2-proven footprint)
    half8_t bw[12][4];
    #pragma unroll
    for (int kt = 0; kt < 12; ++kt)
        #pragma unroll
        for (int ct = 0; ct < 4; ++ct)
            bw[kt][ct] = *(const half8_t*)(WhT + (size_t)(wbase + ct * 16 + l15) * DIM + kt * 32 + q * 8);
    #pragma unroll
    for (int kt = 0; kt < 12; ++kt)
        #pragma unroll
        for (int ct = 0; ct < 4; ++ct)
            asm volatile("" : "+v"(bw[kt][ct]));
    // ---- stage LDS A-fragments of W (kt 12..15), per-thread self-read slots
    #pragma unroll
    for (int ktl = 0; ktl < 4; ++ktl)
        #pragma unroll
        for (int ct = 0; ct < 4; ++ct) {
            half8_t v = *(const half8_t*)(WhT + (size_t)(wbase + ct * 16 + l15) * DIM + (12 + ktl) * 32 + q * 8);
            *(half8_t*)(WlA + (size_t)((w * 16 + ct * 4 + ktl) * 512 + l * 8)) = v;
        }

    // ---- per-ct h-write offsets (loop-invariant), R2 slot perm:
    //      kt = w*2+(ct>>1); L = ((ct&1)*2+(q>>1))*16 + l15; slot(L)=(L&3)*16+(L>>2);
    //      elem base = (q&1)*4
    int aw_off[4];
    #pragma unroll
    for (int ct = 0; ct < 4; ++ct) {
        const int kt = w * 2 + (ct >> 1);
        const int Lt = ((ct & 1) * 2 + (q >> 1)) * 16 + l15;
        const int slot = (Lt & 3) * 16 + (Lt >> 2);
        aw_off[ct] = kt * 512 + slot * 8 + (q & 1) * 4;
    }

    // ---- h0: out[0] plane (exact f32 passthrough) + Ah init (f16)
    float* p0 = out + (size_t)(b * 16 + l15) * DIM + wbase + q * 4;
    #pragma unroll
    for (int ct = 0; ct < 4; ++ct) {
        const float4 hv = *(const float4*)(h0 + wbase + ct * 16 + q * 4);
        *(float4*)(p0 + ct * 16) = hv;
        half4_t hh;
        hh[0] = (_Float16)hv.x; hh[1] = (_Float16)hv.y;
        hh[2] = (_Float16)hv.z; hh[3] = (_Float16)hv.w;
        *(half4_t*)(&Ah[0] + aw_off[ct]) = hh;
    }
    __syncthreads();

    const int psl = (l & 3) * 128 + (l >> 2) * 8;          // R2 read slot base (elems)
    const _Float16* pz = Zw + ((size_t)(b * 8 + w) * 64 + l) * 16;
    half8_t z0 = *(const half8_t*)(pz);
    half8_t z1 = *(const half8_t*)(pz + 8);
    float* pout = out + (size_t)(BATCH + b * 16 + l15) * DIM + wbase + q * 4;   // t=1 plane

    for (int t = 0; t < T_STEPS - 1; ++t) {
        // acc init = z_t (f16 -> f32)
        f32x4 acc[4];
        #pragma unroll
        for (int ct = 0; ct < 4; ++ct)
            #pragma unroll
            for (int rg = 0; rg < 4; ++rg) {
                const int i = ct * 4 + rg;
                acc[ct][rg] = (float)(i < 8 ? z0[i] : z1[i - 8]);
            }
        // prefetch z_{t+1} (stays in flight across the MFMA phase)
        half8_t zn0 = *(const half8_t*)(pz + (size_t)(t + 1) * 32768);
        half8_t zn1 = *(const half8_t*)(pz + (size_t)(t + 1) * 32768 + 8);

        // ---- MFMA phase: 16 k-tiles x 4 col-tiles = 64 MFMA (A=W, B=h)
        #pragma unroll
        for (int kt = 0; kt < 12; ++kt) {
            half8_t hf = *(const half8_t*)(Ah + kt * 512 + psl);
            #pragma unroll
            for (int ct = 0; ct < 4; ++ct)
                acc[ct] = __builtin_amdgcn_mfma_f32_16x16x32_f16(bw[kt][ct], hf, acc[ct], 0, 0, 0);
        }
        #pragma unroll
        for (int ktl = 0; ktl < 4; ++ktl) {
            half8_t hf = *(const half8_t*)(Ah + (12 + ktl) * 512 + psl);
            #pragma unroll
            for (int ct = 0; ct < 4; ++ct) {
                half8_t wf = *(const half8_t*)(WlA + (size_t)((w * 16 + ct * 4 + ktl) * 512 + l * 8));
                acc[ct] = __builtin_amdgcn_mfma_f32_16x16x32_f16(wf, hf, acc[ct], 0, 0, 0);
            }
        }

        // mid barrier (R2): all waves' Ah reads done before anyone overwrites (single buffer)
        asm volatile("s_waitcnt lgkmcnt(0)\n\ts_barrier" ::: "memory");

        // ---- epilogue: tanh, ONE b64 h-write + ONE b128 out-store per ct
        #pragma unroll
        for (int ct = 0; ct < 4; ++ct) {
            float4 hv;
            hv.x = fast_tanh(acc[ct][0]);
            hv.y = fast_tanh(acc[ct][1]);
            hv.z = fast_tanh(acc[ct][2]);
            hv.w = fast_tanh(acc[ct][3]);
            half4_t hh;
            hh[0] = (_Float16)hv.x; hh[1] = (_Float16)hv.y;
            hh[2] = (_Float16)hv.z; hh[3] = (_Float16)hv.w;
            *(half4_t*)(&Ah[0] + aw_off[ct]) = hh;
            *(float4*)(pout + ct * 16) = hv;
        }

        z0 = zn0; z1 = zn1;
        pout += BATCH * DIM;
        // end barrier (R2): h(t+1) writes drained (LDS only); out-stores / z-prefetch in flight
        asm volatile("s_waitcnt lgkmcnt(0)\n\ts_barrier" ::: "memory");
    }
}

extern "C" void kernel_launch(void* const* d_in, const int* in_sizes, int n_in,
                              void* d_out, int out_size, void* d_ws, size_t ws_size,
                              hipStream_t stream) {
    const float* X    = (const float*)d_in[0];   // [512][64][512]
    const float* W    = (const float*)d_in[1];   // [1024][512]
    const float* bias = (const float*)d_in[2];   // [512]
    const float* h0   = (const float*)d_in[3];   // [512]
    float* out = (float*)d_out;

    char* ws = (char*)d_ws;
    unsigned short* WxT = (unsigned short*)(ws);                 //    524,288 B
    _Float16*       WhT = (_Float16*)(ws + 524288);              //    524,288 B  [col][k] f16
    _Float16*       Zws = (_Float16*)(ws + 1048576);             // 33,554,432 B  frag-ordered Z
                                                                  // total 34,603,008 B

    dim3 tb(32, 8);
    tr_cvt_kernel<<<dim3(16, 16), tb, 0, stream>>>(W, WxT);                    // Wx^T bf16
    tr_cvt_f16_kernel<<<dim3(16, 16), tb, 0, stream>>>(W + 512 * 512, WhT);    // Wh^T f16
    gemm_z_kernel<<<dim3(4, 256), 256, 0, stream>>>(X, WxT, bias, Zws);
    rnn_mfma_kernel<<<4, 512, 0, stream>>>(Zws, WhT, h0, out);
}